// Round 13
// baseline (203.931 us; speedup 1.0000x reference)
//
#include <hip/hip_runtime.h>
#include <hip/hip_bf16.h>

// Self-attention: y = softmax_causal((Xq Wq^T + bq)(Xk Wk^T + bk)^T / 32) (Xv Wv^T + bv)
// N=4, K=2048, M=DQ=DV=1024.
//
// Pipeline (bf16 MFMA, f32 accumulate):
//   0) cvt6          : {query,key,value,Wq,Wk,Wv} -> bf16, one launch
//   1) gemm_projb    : merged projections, all-bf16 128^2 2-phase (r11/r12: 62us, 830 TF).
//                      z==2 writes V transposed to Vt via LDS bounce (2-way-conflict
//                      pattern = free per m136; r12 confirmed swizzle-invariant).
//   2) gemm_bt<1>    : S = Qs . Kp^T (f32), grid (16,16,4), causal early-exit
//   3) softmax_causal: WAVE-PER-ROW causal softmax (4 rows/block, shuffle-only,
//                      no LDS/barriers), bf16 P in-place over S (row stride 4096)
//   4) gemm_bt<2>    : y = P . Vt, K truncated at causal bound; row-block permutation
//                      balances per-CU physical pair (p,p+256) work to 17 tiles
//
// Workspace (128 MiB): QKV bf16 [3][8192][1024] @0 (z=2 slab unused); Vt @48M;
//   S f32 [4][2048][2048] @64M (aliased per-row by P bf16, row stride 4096);
//   overlap (dead before S): Xb bf16 [3][8192][1024] @64M; Wb @112M

typedef __bf16 bf16x8 __attribute__((ext_vector_type(8)));
typedef __bf16 bf16x4 __attribute__((ext_vector_type(4)));
typedef float  f32x4  __attribute__((ext_vector_type(4)));

#define BM 128
#define BN 128
#define BKK 64

// byte offset into a [rows][64] bf16 LDS tile, 16B slots XOR-swizzled by row
__device__ __forceinline__ int swz(int row, int slot) {
    return row * 128 + (((slot) ^ (row & 7)) << 4);
}

__device__ __forceinline__ void gload16(const __bf16* g, __bf16* l) {
    __builtin_amdgcn_global_load_lds((const __attribute__((address_space(1))) void*)g,
                                     (__attribute__((address_space(3))) void*)l, 16, 0, 0);
}

// T1: bijective XCD-chunked remap (m204)
__device__ __forceinline__ void xcd_remap(int& bx, int& by, int& bz) {
    const int nx = gridDim.x, ny = gridDim.y;
    const int nwg = nx * ny * gridDim.z;
    const int flat = blockIdx.x + nx * (blockIdx.y + ny * blockIdx.z);
    const int q = nwg >> 3, r = nwg & 7;
    const int xcd = flat & 7, idx = flat >> 3;
    const int l = (xcd < r ? xcd * (q + 1) : r * (q + 1) + (xcd - r) * q) + idx;
    bx = l % nx; by = (l / nx) % ny; bz = l / (nx * ny);
}

// ============== merged projection GEMM (all-bf16, r5 structure + Vt epilogue) ==============
__global__ __launch_bounds__(256)
void gemm_projb(const __bf16* __restrict__ Xb, const __bf16* __restrict__ Wb,
                const float* __restrict__ b0, const float* __restrict__ b1,
                const float* __restrict__ b2, float scaleQ,
                __bf16* __restrict__ QKV, __bf16* __restrict__ Vt)
{
    __shared__ char smem[65536];
    __bf16* smA = (__bf16*)smem;            // [2][128*64]
    __bf16* smB = (__bf16*)(smem + 32768);  // [2][128*64]

    int bx, by, bz;
    xcd_remap(bx, by, bz);                  // grid (8, 64, 3)
    const int m0 = by * BM, n0 = bx * BN;
    const int z = bz;
    const __bf16* Az = Xb + (long)z * 8388608L;
    const __bf16* Bz = Wb + (long)z * 1048576L;

    const int tid = threadIdx.x;
    const int wid = tid >> 6, lane = tid & 63;
    const int wm = (wid >> 1) * 64, wn = (wid & 1) * 64;  // 2x2 waves, 64x64 each
    const int g = lane >> 4, li = lane & 15;
    const int rl = lane >> 3;               // row within 8-row segment
    const int sg = (lane & 7) ^ rl;         // pre-swizzled 16B slot in global

    f32x4 acc[4][4];
#pragma unroll
    for (int i = 0; i < 4; i++)
#pragma unroll
        for (int j = 0; j < 4; j++)
            acc[i][j] = (f32x4){0.f, 0.f, 0.f, 0.f};

    auto STAGE = [&](int buf, int k0) {     // async global->LDS, both operands
#pragma unroll
        for (int i = 0; i < 4; i++) {
            const int seg = i * 4 + wid;
            const int r = seg * 8 + rl;
            gload16(Az + (long)(m0 + r) * 1024 + k0 + sg * 8, smA + buf * 8192 + seg * 512);
            gload16(Bz + (long)(n0 + r) * 1024 + k0 + sg * 8, smB + buf * 8192 + seg * 512);
        }
    };

    auto COMPUTE = [&](int buf) {
        const char* bA = (const char*)(smA + buf * 8192);
        const char* bB = (const char*)(smB + buf * 8192);
#pragma unroll
        for (int kk = 0; kk < 2; kk++) {
            const int slot = kk * 4 + g;
            bf16x8 af[4], bfv[4];
#pragma unroll
            for (int t = 0; t < 4; t++)
                af[t] = *(const bf16x8*)(bA + swz(wm + t * 16 + li, slot));
#pragma unroll
            for (int t = 0; t < 4; t++)
                bfv[t] = *(const bf16x8*)(bB + swz(wn + t * 16 + li, slot));
#pragma unroll
            for (int tm = 0; tm < 4; tm++)
#pragma unroll
                for (int tn = 0; tn < 4; tn++)
                    acc[tm][tn] = __builtin_amdgcn_mfma_f32_16x16x32_bf16(
                        af[tm], bfv[tn], acc[tm][tn], 0, 0, 0);
        }
    };

    const int nt = 16;                      // K = 1024 / 64
    STAGE(0, 0);
    __syncthreads();
    int cur = 0;
    for (int t = 0; t < nt - 1; ++t) {
        STAGE(cur ^ 1, (t + 1) * BKK);      // prefetch flies under compute
        COMPUTE(cur);
        __syncthreads();
        cur ^= 1;
    }
    COMPUTE(cur);

    // ---- epilogue: C/D layout col = lane&15, row = 4*(lane>>4)+reg ----
    if (z < 2) {
        const float scale = (z == 0) ? scaleQ : 1.f;
        const float* bias = (z == 0) ? b0 : b1;
        __bf16* C = QKV + (long)z * 8388608L;
#pragma unroll
        for (int tm = 0; tm < 4; tm++)
#pragma unroll
            for (int tn = 0; tn < 4; tn++) {
                const int row = m0 + wm + tm * 16 + g * 4;
                const int col = n0 + wn + tn * 16 + li;
                const float b = bias[col];
#pragma unroll
                for (int j = 0; j < 4; j++)
                    C[(long)(row + j) * 1024 + col] = (__bf16)((acc[tm][tn][j] + b) * scale);
            }
    } else {
        // V: bias-add, write TRANSPOSED to Vt via LDS bounce (2-way pattern, free)
        __syncthreads();                    // done reading smA/smB; reuse as T[128][136]
        __bf16* T = (__bf16*)smem;
#pragma unroll
        for (int tm = 0; tm < 4; tm++)
#pragma unroll
            for (int tn = 0; tn < 4; tn++) {
                const int rowl = wm + tm * 16 + g * 4;      // k-local
                const int coll = wn + tn * 16 + li;         // d-local
                const float b = b2[n0 + coll];
#pragma unroll
                for (int j = 0; j < 4; j++)
                    T[coll * 136 + rowl + j] = (__bf16)(acc[tm][tn][j] + b);
            }
        __syncthreads();
        const long nb = m0 >> 11;           // batch index
        const int kbase = m0 & 2047;
        __bf16* Vtb = Vt + nb * 2097152L;   // [1024][2048] per batch
#pragma unroll
        for (int it = 0; it < 8; it++) {
            const int lin = tid + 256 * it;  // 0..2047
            const int c = lin >> 4;          // d-local 0..127
            const int r0 = (lin & 15) * 8;   // k-local 0..120
            bf16x8 v = *(const bf16x8*)(T + c * 136 + r0);
            *(bf16x8*)(Vtb + (long)(n0 + c) * 2048 + kbase + r0) = v;
        }
    }
}

// ================= 128x128 2-phase GEMM for scores / PV =================
// MODE 1: C f32; causal block skip (early-exit).
// MODE 2: C f32; K truncated at m0+BM; by-permutation balances per-CU pair work.
template<int MODE>
__global__ __launch_bounds__(256)
void gemm_bt(const __bf16* __restrict__ Ap, const __bf16* __restrict__ Bp,
             void* __restrict__ Cp, int Kd, int lda, int ldb, int ldc,
             long strideA, long strideB, long strideC)
{
    __shared__ __bf16 smA[2][BM * BKK];
    __shared__ __bf16 smB[2][BN * BKK];

    int bx, by, bz;
    xcd_remap(bx, by, bz);

    if (MODE == 2) {
        // balance CU pairs (logical by, by+4): f(b)+f(b+4) == 15 for all b
        const int t = by >> 2;
        by = (t == 0) ? by : (t == 1) ? 19 - by : (t == 2) ? by - 4 : 23 - by;
    }

    const int tid = threadIdx.x;
    const int m0 = by * BM;
    const int n0 = bx * BN;
    if (MODE == 1 && n0 > m0) return;   // fully-masked causal block

    const long z = bz;
    int kEnd = Kd;
    if (MODE == 2) { int lim = m0 + BM; kEnd = lim < Kd ? lim : Kd; }

    const int wid = tid >> 6, lane = tid & 63;
    const int wm = (wid >> 1) * 64, wn = (wid & 1) * 64;
    const int g = lane >> 4, li = lane & 15;
    const int rl = lane >> 3;
    const int sg = (lane & 7) ^ rl;
    const __bf16* Az = Ap + z * strideA;
    const __bf16* Bz = Bp + z * strideB;

    f32x4 acc[4][4];
    for (int i = 0; i < 4; i++)
        for (int j = 0; j < 4; j++)
            acc[i][j] = (f32x4){0.f, 0.f, 0.f, 0.f};

    auto STAGE = [&](int buf, int k0) {
        for (int i = 0; i < 4; i++) {
            const int seg = i * 4 + wid;
            const int r = seg * 8 + rl;
            gload16(Az + (long)(m0 + r) * lda + k0 + sg * 8, &smA[buf][seg * 512]);
            gload16(Bz + (long)(n0 + r) * ldb + k0 + sg * 8, &smB[buf][seg * 512]);
        }
    };

    auto COMPUTE = [&](int buf) {
        for (int kk = 0; kk < 2; kk++) {
            const int slot = kk * 4 + g;
            bf16x8 af[4], bfv[4];
            for (int t = 0; t < 4; t++)
                af[t] = *(const bf16x8*)((const char*)&smA[buf][0] + swz(wm + t * 16 + li, slot));
            for (int t = 0; t < 4; t++)
                bfv[t] = *(const bf16x8*)((const char*)&smB[buf][0] + swz(wn + t * 16 + li, slot));
            for (int tm = 0; tm < 4; tm++)
                for (int tn = 0; tn < 4; tn++)
                    acc[tm][tn] = __builtin_amdgcn_mfma_f32_16x16x32_bf16(
                        af[tm], bfv[tn], acc[tm][tn], 0, 0, 0);
        }
    };

    const int nt = kEnd / BKK;
    STAGE(0, 0);
    __syncthreads();
    int cur = 0;
    for (int t = 0; t < nt - 1; ++t) {
        STAGE(cur ^ 1, (t + 1) * BKK);
        COMPUTE(cur);
        __syncthreads();
        cur ^= 1;
    }
    COMPUTE(cur);

    for (int tm = 0; tm < 4; tm++) {
        for (int tn = 0; tn < 4; tn++) {
            const int row = m0 + wm + tm * 16 + g * 4;
            const int col = n0 + wn + tn * 16 + li;
            float* C = (float*)Cp + z * strideC;
            for (int j = 0; j < 4; j++)
                C[(long)(row + j) * ldc + col] = acc[tm][tn][j];
        }
    }
}

// f32 -> bf16 for 6 tensors in one launch; blockIdx.y selects tensor
__global__ __launch_bounds__(256)
void cvt6(const float* __restrict__ s0, const float* __restrict__ s1,
          const float* __restrict__ s2, const float* __restrict__ s3,
          const float* __restrict__ s4, const float* __restrict__ s5,
          __bf16* __restrict__ dX, __bf16* __restrict__ dW)
{
    const int y = blockIdx.y;
    const float* src = y == 0 ? s0 : y == 1 ? s1 : y == 2 ? s2
                     : y == 3 ? s3 : y == 4 ? s4 : s5;
    const long n = (y < 3) ? 8388608L : 1048576L;
    __bf16* dst = (y < 3) ? dX + (long)y * 8388608L : dW + (long)(y - 3) * 1048576L;

    long i = ((long)blockIdx.x * 256 + threadIdx.x) * 8;
    const long stride = (long)gridDim.x * 2048;
    for (; i < n; i += stride) {
        float4 a = *(const float4*)(src + i);
        float4 b = *(const float4*)(src + i + 4);
        bf16x8 v;
        v[0] = (__bf16)a.x; v[1] = (__bf16)a.y; v[2] = (__bf16)a.z; v[3] = (__bf16)a.w;
        v[4] = (__bf16)b.x; v[5] = (__bf16)b.y; v[6] = (__bf16)b.z; v[7] = (__bf16)b.w;
        *(bf16x8*)(dst + i) = v;
    }
}

// WAVE-PER-ROW causal softmax. One 64-lane wave owns row q: float4 loads,
// shuffle-only reductions (no LDS, no barriers), bf16x4 stores in-place over S
// (row stride 4096 elems). Writes k in [0, 256*ni) — zeros beyond q; PV's causal
// K-truncation reads only k < ((q>>7)+1)*128 <= 256*ni, all covered.
__global__ __launch_bounds__(256)
void softmax_causal(float* __restrict__ S)
{
    const int q = (blockIdx.x << 2) + (threadIdx.x >> 6);
    const int lane = threadIdx.x & 63;
    const long rowoff = (long)blockIdx.y * 2048 + q;
    const float* Srow = S + rowoff * 2048;
    __bf16* Prow = (__bf16*)S + rowoff * 4096;   // aliases the same row
    const int ni = ((q | 127) + 256) >> 8;       // 256-elem chunks covering live k

    float4 v[8];
    float mx = -1e30f;
    for (int i = 0; i < ni; i++) {
        const int e0 = ((i << 6) + lane) << 2;
        float4 t = *(const float4*)(Srow + e0);
        t.x = (e0     <= q) ? t.x : -1e30f;
        t.y = (e0 + 1 <= q) ? t.y : -1e30f;
        t.z = (e0 + 2 <= q) ? t.z : -1e30f;
        t.w = (e0 + 3 <= q) ? t.w : -1e30f;
        v[i] = t;
        mx = fmaxf(mx, fmaxf(fmaxf(t.x, t.y), fmaxf(t.z, t.w)));
    }
    for (int off = 32; off; off >>= 1) mx = fmaxf(mx, __shfl_xor(mx, off));

    float s = 0.f;
    for (int i = 0; i < ni; i++) {
        float4 t = v[i];
        t.x = __expf(t.x - mx); t.y = __expf(t.y - mx);
        t.z = __expf(t.z - mx); t.w = __expf(t.w - mx);
        v[i] = t;
        s += (t.x + t.y) + (t.z + t.w);
    }
    for (int off = 32; off; off >>= 1) s += __shfl_xor(s, off);
    const float inv = 1.f / s;

    // wave-lockstep: all Srow loads above precede these aliasing stores
    for (int i = 0; i < ni; i++) {
        const int e0 = ((i << 6) + lane) << 2;
        bf16x4 o;
        o[0] = (__bf16)(v[i].x * inv); o[1] = (__bf16)(v[i].y * inv);
        o[2] = (__bf16)(v[i].z * inv); o[3] = (__bf16)(v[i].w * inv);
        *(bf16x4*)(Prow + e0) = o;
    }
}

extern "C" void kernel_launch(void* const* d_in, const int* in_sizes, int n_in,
                              void* d_out, int out_size, void* d_ws, size_t ws_size,
                              hipStream_t stream) {
    const float* query = (const float*)d_in[0];
    const float* key   = (const float*)d_in[1];
    const float* value = (const float*)d_in[2];
    // d_in[3] = mask : deterministic causal triu -> applied by index, ignored here
    const float* Wq = (const float*)d_in[4];
    const float* bq = (const float*)d_in[5];
    const float* Wk = (const float*)d_in[6];
    const float* bk = (const float*)d_in[7];
    const float* Wv = (const float*)d_in[8];
    const float* bv = (const float*)d_in[9];
    float* out = (float*)d_out;

    char* ws = (char*)d_ws;
    const long MB = 1L << 20;
    __bf16* QKV = (__bf16*)(ws);             // [3][8192][1024] (z=2 slab unused)
    __bf16* Vt  = (__bf16*)(ws + 48 * MB);   // [4][1024][2048]
    float*  S   = (float*) (ws + 64 * MB);   // [4][2048][2048]
    __bf16* Xb  = (__bf16*)(ws + 64 * MB);   // overlap, dead before S written
    __bf16* Wb  = (__bf16*)(ws + 112 * MB);

    const dim3 blk(256);

    // 0) f32 -> bf16 conversions (single launch)
    cvt6<<<dim3(1024, 6), blk, 0, stream>>>(query, key, value, Wq, Wk, Wv, Xb, Wb);

    // 1) merged projections (all-bf16; z==2 writes Vt transposed)
    gemm_projb<<<dim3(8, 64, 3), blk, 0, stream>>>(
        Xb, Wb, bq, bk, bv, 1.f / 32.f, QKV, Vt);

    // 2) scores S[n][q][k] = Qs[q].Kp[k]  (causal early-exit)
    gemm_bt<1><<<dim3(16, 16, 4), blk, 0, stream>>>(QKV, QKV + 8388608L, S,
        1024, 1024, 1024, 2048, 2048L * 1024, 2048L * 1024, 2048L * 2048);

    // 3) causal softmax (wave-per-row, in-place S -> P bf16)
    softmax_causal<<<dim3(512, 4), blk, 0, stream>>>(S);

    // 4) y = P . V via Vt, causal K truncation, pair-balanced row order
    gemm_bt<2><<<dim3(8, 16, 4), blk, 0, stream>>>((__bf16*)S, Vt, out,
        2048, 4096, 2048, 1024, 2048L * 4096, 1024L * 2048, 2048L * 1024);
}

// Round 14
// 177.044 us; speedup vs baseline: 1.1519x; 1.1519x over previous
//
#include <hip/hip_runtime.h>
#include <hip/hip_bf16.h>

// Self-attention: y = softmax_causal((Xq Wq^T + bq)(Xk Wk^T + bk)^T / 32) (Xv Wv^T + bv)
// N=4, K=2048, M=DQ=DV=1024.
//
// Pipeline (bf16 MFMA, f32 accumulate):
//   0) cvt6          : {query,key,value,Wq,Wk,Wv} -> bf16, one launch
//   1) gemm_projb    : merged projections, all-bf16 128^2 2-phase (62us, 830 TF).
//                      z==2 writes V transposed to Vt via LDS bounce.
//   2) gemm_bt<1>    : S = Qs . Kp^T (f32), grid (16,16,4), causal early-exit
//   3) softmax_causal: wave-per-row causal softmax, COMPILE-TIME-UNROLLED chunk
//                      loops with i<ni guards (r13's runtime-bound loops sent
//                      v[8] to scratch: VGPR=12, 132us — rule #20 violation)
//   4) gemm_bt<2>    : y = P . Vt, K truncated at causal bound, pair-balanced rows
//
// Workspace (128 MiB): QKV bf16 [3][8192][1024] @0 (z=2 slab unused); Vt @48M;
//   S f32 [4][2048][2048] @64M (aliased per-row by P bf16, row stride 4096);
//   overlap (dead before S): Xb bf16 [3][8192][1024] @64M; Wb @112M

typedef __bf16 bf16x8 __attribute__((ext_vector_type(8)));
typedef __bf16 bf16x4 __attribute__((ext_vector_type(4)));
typedef float  f32x4  __attribute__((ext_vector_type(4)));

#define BM 128
#define BN 128
#define BKK 64

// byte offset into a [rows][64] bf16 LDS tile, 16B slots XOR-swizzled by row
__device__ __forceinline__ int swz(int row, int slot) {
    return row * 128 + (((slot) ^ (row & 7)) << 4);
}

__device__ __forceinline__ void gload16(const __bf16* g, __bf16* l) {
    __builtin_amdgcn_global_load_lds((const __attribute__((address_space(1))) void*)g,
                                     (__attribute__((address_space(3))) void*)l, 16, 0, 0);
}

// T1: bijective XCD-chunked remap (m204)
__device__ __forceinline__ void xcd_remap(int& bx, int& by, int& bz) {
    const int nx = gridDim.x, ny = gridDim.y;
    const int nwg = nx * ny * gridDim.z;
    const int flat = blockIdx.x + nx * (blockIdx.y + ny * blockIdx.z);
    const int q = nwg >> 3, r = nwg & 7;
    const int xcd = flat & 7, idx = flat >> 3;
    const int l = (xcd < r ? xcd * (q + 1) : r * (q + 1) + (xcd - r) * q) + idx;
    bx = l % nx; by = (l / nx) % ny; bz = l / (nx * ny);
}

// ============== merged projection GEMM (all-bf16, r5 structure + Vt epilogue) ==============
__global__ __launch_bounds__(256)
void gemm_projb(const __bf16* __restrict__ Xb, const __bf16* __restrict__ Wb,
                const float* __restrict__ b0, const float* __restrict__ b1,
                const float* __restrict__ b2, float scaleQ,
                __bf16* __restrict__ QKV, __bf16* __restrict__ Vt)
{
    __shared__ char smem[65536];
    __bf16* smA = (__bf16*)smem;            // [2][128*64]
    __bf16* smB = (__bf16*)(smem + 32768);  // [2][128*64]

    int bx, by, bz;
    xcd_remap(bx, by, bz);                  // grid (8, 64, 3)
    const int m0 = by * BM, n0 = bx * BN;
    const int z = bz;
    const __bf16* Az = Xb + (long)z * 8388608L;
    const __bf16* Bz = Wb + (long)z * 1048576L;

    const int tid = threadIdx.x;
    const int wid = tid >> 6, lane = tid & 63;
    const int wm = (wid >> 1) * 64, wn = (wid & 1) * 64;  // 2x2 waves, 64x64 each
    const int g = lane >> 4, li = lane & 15;
    const int rl = lane >> 3;               // row within 8-row segment
    const int sg = (lane & 7) ^ rl;         // pre-swizzled 16B slot in global

    f32x4 acc[4][4];
#pragma unroll
    for (int i = 0; i < 4; i++)
#pragma unroll
        for (int j = 0; j < 4; j++)
            acc[i][j] = (f32x4){0.f, 0.f, 0.f, 0.f};

    auto STAGE = [&](int buf, int k0) {     // async global->LDS, both operands
#pragma unroll
        for (int i = 0; i < 4; i++) {
            const int seg = i * 4 + wid;
            const int r = seg * 8 + rl;
            gload16(Az + (long)(m0 + r) * 1024 + k0 + sg * 8, smA + buf * 8192 + seg * 512);
            gload16(Bz + (long)(n0 + r) * 1024 + k0 + sg * 8, smB + buf * 8192 + seg * 512);
        }
    };

    auto COMPUTE = [&](int buf) {
        const char* bA = (const char*)(smA + buf * 8192);
        const char* bB = (const char*)(smB + buf * 8192);
#pragma unroll
        for (int kk = 0; kk < 2; kk++) {
            const int slot = kk * 4 + g;
            bf16x8 af[4], bfv[4];
#pragma unroll
            for (int t = 0; t < 4; t++)
                af[t] = *(const bf16x8*)(bA + swz(wm + t * 16 + li, slot));
#pragma unroll
            for (int t = 0; t < 4; t++)
                bfv[t] = *(const bf16x8*)(bB + swz(wn + t * 16 + li, slot));
#pragma unroll
            for (int tm = 0; tm < 4; tm++)
#pragma unroll
                for (int tn = 0; tn < 4; tn++)
                    acc[tm][tn] = __builtin_amdgcn_mfma_f32_16x16x32_bf16(
                        af[tm], bfv[tn], acc[tm][tn], 0, 0, 0);
        }
    };

    const int nt = 16;                      // K = 1024 / 64
    STAGE(0, 0);
    __syncthreads();
    int cur = 0;
    for (int t = 0; t < nt - 1; ++t) {
        STAGE(cur ^ 1, (t + 1) * BKK);      // prefetch flies under compute
        COMPUTE(cur);
        __syncthreads();
        cur ^= 1;
    }
    COMPUTE(cur);

    // ---- epilogue: C/D layout col = lane&15, row = 4*(lane>>4)+reg ----
    if (z < 2) {
        const float scale = (z == 0) ? scaleQ : 1.f;
        const float* bias = (z == 0) ? b0 : b1;
        __bf16* C = QKV + (long)z * 8388608L;
#pragma unroll
        for (int tm = 0; tm < 4; tm++)
#pragma unroll
            for (int tn = 0; tn < 4; tn++) {
                const int row = m0 + wm + tm * 16 + g * 4;
                const int col = n0 + wn + tn * 16 + li;
                const float b = bias[col];
#pragma unroll
                for (int j = 0; j < 4; j++)
                    C[(long)(row + j) * 1024 + col] = (__bf16)((acc[tm][tn][j] + b) * scale);
            }
    } else {
        // V: bias-add, write TRANSPOSED to Vt via LDS bounce (2-way pattern, free)
        __syncthreads();                    // done reading smA/smB; reuse as T[128][136]
        __bf16* T = (__bf16*)smem;
#pragma unroll
        for (int tm = 0; tm < 4; tm++)
#pragma unroll
            for (int tn = 0; tn < 4; tn++) {
                const int rowl = wm + tm * 16 + g * 4;      // k-local
                const int coll = wn + tn * 16 + li;         // d-local
                const float b = b2[n0 + coll];
#pragma unroll
                for (int j = 0; j < 4; j++)
                    T[coll * 136 + rowl + j] = (__bf16)(acc[tm][tn][j] + b);
            }
        __syncthreads();
        const long nb = m0 >> 11;           // batch index
        const int kbase = m0 & 2047;
        __bf16* Vtb = Vt + nb * 2097152L;   // [1024][2048] per batch
#pragma unroll
        for (int it = 0; it < 8; it++) {
            const int lin = tid + 256 * it;  // 0..2047
            const int c = lin >> 4;          // d-local 0..127
            const int r0 = (lin & 15) * 8;   // k-local 0..120
            bf16x8 v = *(const bf16x8*)(T + c * 136 + r0);
            *(bf16x8*)(Vtb + (long)(n0 + c) * 2048 + kbase + r0) = v;
        }
    }
}

// ================= 128x128 2-phase GEMM for scores / PV =================
// MODE 1: C f32; causal block skip (early-exit).
// MODE 2: C f32; K truncated at m0+BM; by-permutation balances per-CU pair work.
template<int MODE>
__global__ __launch_bounds__(256)
void gemm_bt(const __bf16* __restrict__ Ap, const __bf16* __restrict__ Bp,
             void* __restrict__ Cp, int Kd, int lda, int ldb, int ldc,
             long strideA, long strideB, long strideC)
{
    __shared__ __bf16 smA[2][BM * BKK];
    __shared__ __bf16 smB[2][BN * BKK];

    int bx, by, bz;
    xcd_remap(bx, by, bz);

    if (MODE == 2) {
        // balance CU pairs (logical by, by+4): f(b)+f(b+4) == 15 for all b
        const int t = by >> 2;
        by = (t == 0) ? by : (t == 1) ? 19 - by : (t == 2) ? by - 4 : 23 - by;
    }

    const int tid = threadIdx.x;
    const int m0 = by * BM;
    const int n0 = bx * BN;
    if (MODE == 1 && n0 > m0) return;   // fully-masked causal block

    const long z = bz;
    int kEnd = Kd;
    if (MODE == 2) { int lim = m0 + BM; kEnd = lim < Kd ? lim : Kd; }

    const int wid = tid >> 6, lane = tid & 63;
    const int wm = (wid >> 1) * 64, wn = (wid & 1) * 64;
    const int g = lane >> 4, li = lane & 15;
    const int rl = lane >> 3;
    const int sg = (lane & 7) ^ rl;
    const __bf16* Az = Ap + z * strideA;
    const __bf16* Bz = Bp + z * strideB;

    f32x4 acc[4][4];
    for (int i = 0; i < 4; i++)
        for (int j = 0; j < 4; j++)
            acc[i][j] = (f32x4){0.f, 0.f, 0.f, 0.f};

    auto STAGE = [&](int buf, int k0) {
        for (int i = 0; i < 4; i++) {
            const int seg = i * 4 + wid;
            const int r = seg * 8 + rl;
            gload16(Az + (long)(m0 + r) * lda + k0 + sg * 8, &smA[buf][seg * 512]);
            gload16(Bz + (long)(n0 + r) * ldb + k0 + sg * 8, &smB[buf][seg * 512]);
        }
    };

    auto COMPUTE = [&](int buf) {
        for (int kk = 0; kk < 2; kk++) {
            const int slot = kk * 4 + g;
            bf16x8 af[4], bfv[4];
            for (int t = 0; t < 4; t++)
                af[t] = *(const bf16x8*)((const char*)&smA[buf][0] + swz(wm + t * 16 + li, slot));
            for (int t = 0; t < 4; t++)
                bfv[t] = *(const bf16x8*)((const char*)&smB[buf][0] + swz(wn + t * 16 + li, slot));
            for (int tm = 0; tm < 4; tm++)
                for (int tn = 0; tn < 4; tn++)
                    acc[tm][tn] = __builtin_amdgcn_mfma_f32_16x16x32_bf16(
                        af[tm], bfv[tn], acc[tm][tn], 0, 0, 0);
        }
    };

    const int nt = kEnd / BKK;
    STAGE(0, 0);
    __syncthreads();
    int cur = 0;
    for (int t = 0; t < nt - 1; ++t) {
        STAGE(cur ^ 1, (t + 1) * BKK);
        COMPUTE(cur);
        __syncthreads();
        cur ^= 1;
    }
    COMPUTE(cur);

    for (int tm = 0; tm < 4; tm++) {
        for (int tn = 0; tn < 4; tn++) {
            const int row = m0 + wm + tm * 16 + g * 4;
            const int col = n0 + wn + tn * 16 + li;
            float* C = (float*)Cp + z * strideC;
            for (int j = 0; j < 4; j++)
                C[(long)(row + j) * ldc + col] = acc[tm][tn][j];
        }
    }
}

// f32 -> bf16 for 6 tensors in one launch; blockIdx.y selects tensor
__global__ __launch_bounds__(256)
void cvt6(const float* __restrict__ s0, const float* __restrict__ s1,
          const float* __restrict__ s2, const float* __restrict__ s3,
          const float* __restrict__ s4, const float* __restrict__ s5,
          __bf16* __restrict__ dX, __bf16* __restrict__ dW)
{
    const int y = blockIdx.y;
    const float* src = y == 0 ? s0 : y == 1 ? s1 : y == 2 ? s2
                     : y == 3 ? s3 : y == 4 ? s4 : s5;
    const long n = (y < 3) ? 8388608L : 1048576L;
    __bf16* dst = (y < 3) ? dX + (long)y * 8388608L : dW + (long)(y - 3) * 1048576L;

    long i = ((long)blockIdx.x * 256 + threadIdx.x) * 8;
    const long stride = (long)gridDim.x * 2048;
    for (; i < n; i += stride) {
        float4 a = *(const float4*)(src + i);
        float4 b = *(const float4*)(src + i + 4);
        bf16x8 v;
        v[0] = (__bf16)a.x; v[1] = (__bf16)a.y; v[2] = (__bf16)a.z; v[3] = (__bf16)a.w;
        v[4] = (__bf16)b.x; v[5] = (__bf16)b.y; v[6] = (__bf16)b.z; v[7] = (__bf16)b.w;
        *(bf16x8*)(dst + i) = v;
    }
}

// Wave-per-row causal softmax: one 64-lane wave owns row q. float4 loads,
// shuffle-only reductions, bf16x4 stores in-place over S (row stride 4096).
// Loops are COMPILE-TIME unrolled (8 iters) with i<ni guards so v[] stays in
// registers (rule #20: runtime trip counts send local arrays to scratch).
__global__ __launch_bounds__(256)
void softmax_causal(float* __restrict__ S)
{
    const int q = (blockIdx.x << 2) + (threadIdx.x >> 6);
    const int lane = threadIdx.x & 63;
    const long rowoff = (long)blockIdx.y * 2048 + q;
    const float* Srow = S + rowoff * 2048;
    __bf16* Prow = (__bf16*)S + rowoff * 4096;   // aliases the same row
    const int ni = ((q | 127) + 256) >> 8;       // live 256-elem chunks

    float4 v[8];
    float mx = -1e30f;
#pragma unroll
    for (int i = 0; i < 8; i++) {
        if (i < ni) {
            const int e0 = ((i << 6) + lane) << 2;
            float4 t = *(const float4*)(Srow + e0);
            t.x = (e0     <= q) ? t.x : -1e30f;
            t.y = (e0 + 1 <= q) ? t.y : -1e30f;
            t.z = (e0 + 2 <= q) ? t.z : -1e30f;
            t.w = (e0 + 3 <= q) ? t.w : -1e30f;
            v[i] = t;
            mx = fmaxf(mx, fmaxf(fmaxf(t.x, t.y), fmaxf(t.z, t.w)));
        }
    }
    for (int off = 32; off; off >>= 1) mx = fmaxf(mx, __shfl_xor(mx, off));

    float s = 0.f;
#pragma unroll
    for (int i = 0; i < 8; i++) {
        if (i < ni) {
            float4 t = v[i];
            t.x = __expf(t.x - mx); t.y = __expf(t.y - mx);
            t.z = __expf(t.z - mx); t.w = __expf(t.w - mx);
            v[i] = t;
            s += (t.x + t.y) + (t.z + t.w);
        }
    }
    for (int off = 32; off; off >>= 1) s += __shfl_xor(s, off);
    const float inv = 1.f / s;

    // wave-lockstep: all Srow loads above precede these aliasing stores
#pragma unroll
    for (int i = 0; i < 8; i++) {
        if (i < ni) {
            const int e0 = ((i << 6) + lane) << 2;
            bf16x4 o;
            o[0] = (__bf16)(v[i].x * inv); o[1] = (__bf16)(v[i].y * inv);
            o[2] = (__bf16)(v[i].z * inv); o[3] = (__bf16)(v[i].w * inv);
            *(bf16x4*)(Prow + e0) = o;
        }
    }
}

extern "C" void kernel_launch(void* const* d_in, const int* in_sizes, int n_in,
                              void* d_out, int out_size, void* d_ws, size_t ws_size,
                              hipStream_t stream) {
    const float* query = (const float*)d_in[0];
    const float* key   = (const float*)d_in[1];
    const float* value = (const float*)d_in[2];
    // d_in[3] = mask : deterministic causal triu -> applied by index, ignored here
    const float* Wq = (const float*)d_in[4];
    const float* bq = (const float*)d_in[5];
    const float* Wk = (const float*)d_in[6];
    const float* bk = (const float*)d_in[7];
    const float* Wv = (const float*)d_in[8];
    const float* bv = (const float*)d_in[9];
    float* out = (float*)d_out;

    char* ws = (char*)d_ws;
    const long MB = 1L << 20;
    __bf16* QKV = (__bf16*)(ws);             // [3][8192][1024] (z=2 slab unused)
    __bf16* Vt  = (__bf16*)(ws + 48 * MB);   // [4][1024][2048]
    float*  S   = (float*) (ws + 64 * MB);   // [4][2048][2048]
    __bf16* Xb  = (__bf16*)(ws + 64 * MB);   // overlap, dead before S written
    __bf16* Wb  = (__bf16*)(ws + 112 * MB);

    const dim3 blk(256);

    // 0) f32 -> bf16 conversions (single launch)
    cvt6<<<dim3(1024, 6), blk, 0, stream>>>(query, key, value, Wq, Wk, Wv, Xb, Wb);

    // 1) merged projections (all-bf16; z==2 writes Vt transposed)
    gemm_projb<<<dim3(8, 64, 3), blk, 0, stream>>>(
        Xb, Wb, bq, bk, bv, 1.f / 32.f, QKV, Vt);

    // 2) scores S[n][q][k] = Qs[q].Kp[k]  (causal early-exit)
    gemm_bt<1><<<dim3(16, 16, 4), blk, 0, stream>>>(QKV, QKV + 8388608L, S,
        1024, 1024, 1024, 2048, 2048L * 1024, 2048L * 1024, 2048L * 2048);

    // 3) causal softmax (wave-per-row, register-resident, in-place S -> P bf16)
    softmax_causal<<<dim3(512, 4), blk, 0, stream>>>(S);

    // 4) y = P . V via Vt, causal K truncation, pair-balanced row order
    gemm_bt<2><<<dim3(8, 16, 4), blk, 0, stream>>>((__bf16*)S, Vt, out,
        2048, 4096, 2048, 1024, 2048L * 4096, 1024L * 2048, 2048L * 1024);
}

// Round 15
// 175.626 us; speedup vs baseline: 1.1612x; 1.0081x over previous
//
#include <hip/hip_runtime.h>
#include <hip/hip_bf16.h>

// Self-attention: y = softmax_causal((Xq Wq^T + bq)(Xk Wk^T + bk)^T / 32) (Xv Wv^T + bv)
// N=4, K=2048, M=DQ=DV=1024.
//
// Pipeline (bf16 MFMA, f32 accumulate):
//   0) cvt6          : {query,key,value,Wq,Wk,Wv} -> bf16, one launch
//   1) gemm_projb    : merged projections, all-bf16 128^2 2-phase (62us, 830 TF).
//                      ALL epilogues now LDS-bounce + coalesced bf16x8 stores
//                      (z<2 natural orientation; z==2 transposed to Vt).
//   2) gemm_bt<1>    : S = Qs . Kp^T (f32), TRI-COMPACT grid (136 blocks/batch,
//                      equal work, 68/XCD — r9-verified decode; r10 proved the
//                      apparent r9 regression was machine variance)
//   3) softmax_causal: wave-per-row causal softmax, register-resident (r14: fixed
//                      rule-#20 scratch spill), bf16 P in-place over S
//   4) gemm_bt<2>    : y = P . Vt, K truncated at causal bound, pair-balanced rows
//
// Workspace (128 MiB): QKV bf16 [3][8192][1024] @0 (z=2 slab unused); Vt @48M;
//   S f32 [4][2048][2048] @64M (aliased per-row by P bf16, row stride 4096);
//   overlap (dead before S): Xb bf16 [3][8192][1024] @64M; Wb @112M

typedef __bf16 bf16x8 __attribute__((ext_vector_type(8)));
typedef __bf16 bf16x4 __attribute__((ext_vector_type(4)));
typedef float  f32x4  __attribute__((ext_vector_type(4)));

#define BM 128
#define BN 128
#define BKK 64

// byte offset into a [rows][64] bf16 LDS tile, 16B slots XOR-swizzled by row
__device__ __forceinline__ int swz(int row, int slot) {
    return row * 128 + (((slot) ^ (row & 7)) << 4);
}

__device__ __forceinline__ void gload16(const __bf16* g, __bf16* l) {
    __builtin_amdgcn_global_load_lds((const __attribute__((address_space(1))) void*)g,
                                     (__attribute__((address_space(3))) void*)l, 16, 0, 0);
}

// T1: bijective XCD-chunked remap (m204)
__device__ __forceinline__ void xcd_remap(int& bx, int& by, int& bz) {
    const int nx = gridDim.x, ny = gridDim.y;
    const int nwg = nx * ny * gridDim.z;
    const int flat = blockIdx.x + nx * (blockIdx.y + ny * blockIdx.z);
    const int q = nwg >> 3, r = nwg & 7;
    const int xcd = flat & 7, idx = flat >> 3;
    const int l = (xcd < r ? xcd * (q + 1) : r * (q + 1) + (xcd - r) * q) + idx;
    bx = l % nx; by = (l / nx) % ny; bz = l / (nx * ny);
}

// ============== merged projection GEMM (all-bf16, coalesced epilogues) ==============
__global__ __launch_bounds__(256)
void gemm_projb(const __bf16* __restrict__ Xb, const __bf16* __restrict__ Wb,
                const float* __restrict__ b0, const float* __restrict__ b1,
                const float* __restrict__ b2, float scaleQ,
                __bf16* __restrict__ QKV, __bf16* __restrict__ Vt)
{
    __shared__ char smem[65536];
    __bf16* smA = (__bf16*)smem;            // [2][128*64]
    __bf16* smB = (__bf16*)(smem + 32768);  // [2][128*64]

    int bx, by, bz;
    xcd_remap(bx, by, bz);                  // grid (8, 64, 3)
    const int m0 = by * BM, n0 = bx * BN;
    const int z = bz;
    const __bf16* Az = Xb + (long)z * 8388608L;
    const __bf16* Bz = Wb + (long)z * 1048576L;

    const int tid = threadIdx.x;
    const int wid = tid >> 6, lane = tid & 63;
    const int wm = (wid >> 1) * 64, wn = (wid & 1) * 64;  // 2x2 waves, 64x64 each
    const int g = lane >> 4, li = lane & 15;
    const int rl = lane >> 3;               // row within 8-row segment
    const int sg = (lane & 7) ^ rl;         // pre-swizzled 16B slot in global

    f32x4 acc[4][4];
#pragma unroll
    for (int i = 0; i < 4; i++)
#pragma unroll
        for (int j = 0; j < 4; j++)
            acc[i][j] = (f32x4){0.f, 0.f, 0.f, 0.f};

    auto STAGE = [&](int buf, int k0) {     // async global->LDS, both operands
#pragma unroll
        for (int i = 0; i < 4; i++) {
            const int seg = i * 4 + wid;
            const int r = seg * 8 + rl;
            gload16(Az + (long)(m0 + r) * 1024 + k0 + sg * 8, smA + buf * 8192 + seg * 512);
            gload16(Bz + (long)(n0 + r) * 1024 + k0 + sg * 8, smB + buf * 8192 + seg * 512);
        }
    };

    auto COMPUTE = [&](int buf) {
        const char* bA = (const char*)(smA + buf * 8192);
        const char* bB = (const char*)(smB + buf * 8192);
#pragma unroll
        for (int kk = 0; kk < 2; kk++) {
            const int slot = kk * 4 + g;
            bf16x8 af[4], bfv[4];
#pragma unroll
            for (int t = 0; t < 4; t++)
                af[t] = *(const bf16x8*)(bA + swz(wm + t * 16 + li, slot));
#pragma unroll
            for (int t = 0; t < 4; t++)
                bfv[t] = *(const bf16x8*)(bB + swz(wn + t * 16 + li, slot));
#pragma unroll
            for (int tm = 0; tm < 4; tm++)
#pragma unroll
                for (int tn = 0; tn < 4; tn++)
                    acc[tm][tn] = __builtin_amdgcn_mfma_f32_16x16x32_bf16(
                        af[tm], bfv[tn], acc[tm][tn], 0, 0, 0);
        }
    };

    const int nt = 16;                      // K = 1024 / 64
    STAGE(0, 0);
    __syncthreads();
    int cur = 0;
    for (int t = 0; t < nt - 1; ++t) {
        STAGE(cur ^ 1, (t + 1) * BKK);      // prefetch flies under compute
        COMPUTE(cur);
        __syncthreads();
        cur ^= 1;
    }
    COMPUTE(cur);

    // ---- epilogue: C/D layout col = lane&15, row = 4*(lane>>4)+reg ----
    // All paths bounce through LDS T[128][136] -> coalesced bf16x8 stores.
    __syncthreads();                        // done reading smA/smB; reuse as T
    __bf16* T = (__bf16*)smem;
    if (z < 2) {
        const float scale = (z == 0) ? scaleQ : 1.f;
        const float* bias = (z == 0) ? b0 : b1;
#pragma unroll
        for (int tm = 0; tm < 4; tm++)
#pragma unroll
            for (int tn = 0; tn < 4; tn++) {
                const int rowl = wm + tm * 16 + g * 4;      // block-row
                const int coll = wn + tn * 16 + li;         // block-col
                const float b = bias[n0 + coll];
#pragma unroll
                for (int j = 0; j < 4; j++)
                    T[(rowl + j) * 136 + coll] = (__bf16)((acc[tm][tn][j] + b) * scale);
            }
        __syncthreads();
        __bf16* C = QKV + (long)z * 8388608L;
#pragma unroll
        for (int it = 0; it < 8; it++) {
            const int lin = tid + 256 * it;  // 0..2047
            const int rr = lin >> 4;         // 0..127
            const int c0 = (lin & 15) * 8;   // 0..120
            bf16x8 v = *(const bf16x8*)(T + rr * 136 + c0);
            *(bf16x8*)(C + (long)(m0 + rr) * 1024 + n0 + c0) = v;
        }
    } else {
        // V: bias-add, write TRANSPOSED to Vt (T indexed [col][row])
#pragma unroll
        for (int tm = 0; tm < 4; tm++)
#pragma unroll
            for (int tn = 0; tn < 4; tn++) {
                const int rowl = wm + tm * 16 + g * 4;      // k-local
                const int coll = wn + tn * 16 + li;         // d-local
                const float b = b2[n0 + coll];
#pragma unroll
                for (int j = 0; j < 4; j++)
                    T[coll * 136 + rowl + j] = (__bf16)(acc[tm][tn][j] + b);
            }
        __syncthreads();
        const long nb = m0 >> 11;           // batch index
        const int kbase = m0 & 2047;
        __bf16* Vtb = Vt + nb * 2097152L;   // [1024][2048] per batch
#pragma unroll
        for (int it = 0; it < 8; it++) {
            const int lin = tid + 256 * it;  // 0..2047
            const int c = lin >> 4;          // d-local 0..127
            const int r0 = (lin & 15) * 8;   // k-local 0..120
            bf16x8 v = *(const bf16x8*)(T + c * 136 + r0);
            *(bf16x8*)(Vtb + (long)(n0 + c) * 2048 + kbase + r0) = v;
        }
    }
}

// ================= 128x128 2-phase GEMM for scores / PV =================
// MODE 1: C f32; TRI-COMPACT causal grid (grid.x = 136 triangle-encoded blocks).
// MODE 2: C f32; K truncated at m0+BM; by-permutation balances per-CU pair work.
template<int MODE>
__global__ __launch_bounds__(256)
void gemm_bt(const __bf16* __restrict__ Ap, const __bf16* __restrict__ Bp,
             void* __restrict__ Cp, int Kd, int lda, int ldb, int ldc,
             long strideA, long strideB, long strideC)
{
    __shared__ __bf16 smA[2][BM * BKK];
    __shared__ __bf16 smB[2][BN * BKK];

    int bx, by, bz;
    xcd_remap(bx, by, bz);

    if (MODE == 1) {
        // triangle decode (r9-verified): t -> (row by, col bx), bx <= by
        const int t = bx;
        int r = (int)((sqrtf(8.f * t + 1.f) - 1.f) * 0.5f);
        while ((r + 1) * (r + 2) / 2 <= t) r++;
        while (r * (r + 1) / 2 > t) r--;
        by = r;
        bx = t - r * (r + 1) / 2;
    }
    if (MODE == 2) {
        // balance CU pairs (logical by, by+4): f(b)+f(b+4) == 15 for all b
        const int t = by >> 2;
        by = (t == 0) ? by : (t == 1) ? 19 - by : (t == 2) ? by - 4 : 23 - by;
    }

    const int tid = threadIdx.x;
    const int m0 = by * BM;
    const int n0 = bx * BN;

    const long z = bz;
    int kEnd = Kd;
    if (MODE == 2) { int lim = m0 + BM; kEnd = lim < Kd ? lim : Kd; }

    const int wid = tid >> 6, lane = tid & 63;
    const int wm = (wid >> 1) * 64, wn = (wid & 1) * 64;
    const int g = lane >> 4, li = lane & 15;
    const int rl = lane >> 3;
    const int sg = (lane & 7) ^ rl;
    const __bf16* Az = Ap + z * strideA;
    const __bf16* Bz = Bp + z * strideB;

    f32x4 acc[4][4];
    for (int i = 0; i < 4; i++)
        for (int j = 0; j < 4; j++)
            acc[i][j] = (f32x4){0.f, 0.f, 0.f, 0.f};

    auto STAGE = [&](int buf, int k0) {
        for (int i = 0; i < 4; i++) {
            const int seg = i * 4 + wid;
            const int r = seg * 8 + rl;
            gload16(Az + (long)(m0 + r) * lda + k0 + sg * 8, &smA[buf][seg * 512]);
            gload16(Bz + (long)(n0 + r) * ldb + k0 + sg * 8, &smB[buf][seg * 512]);
        }
    };

    auto COMPUTE = [&](int buf) {
        for (int kk = 0; kk < 2; kk++) {
            const int slot = kk * 4 + g;
            bf16x8 af[4], bfv[4];
            for (int t = 0; t < 4; t++)
                af[t] = *(const bf16x8*)((const char*)&smA[buf][0] + swz(wm + t * 16 + li, slot));
            for (int t = 0; t < 4; t++)
                bfv[t] = *(const bf16x8*)((const char*)&smB[buf][0] + swz(wn + t * 16 + li, slot));
            for (int tm = 0; tm < 4; tm++)
                for (int tn = 0; tn < 4; tn++)
                    acc[tm][tn] = __builtin_amdgcn_mfma_f32_16x16x32_bf16(
                        af[tm], bfv[tn], acc[tm][tn], 0, 0, 0);
        }
    };

    const int nt = kEnd / BKK;
    STAGE(0, 0);
    __syncthreads();
    int cur = 0;
    for (int t = 0; t < nt - 1; ++t) {
        STAGE(cur ^ 1, (t + 1) * BKK);
        COMPUTE(cur);
        __syncthreads();
        cur ^= 1;
    }
    COMPUTE(cur);

    for (int tm = 0; tm < 4; tm++) {
        for (int tn = 0; tn < 4; tn++) {
            const int row = m0 + wm + tm * 16 + g * 4;
            const int col = n0 + wn + tn * 16 + li;
            float* C = (float*)Cp + z * strideC;
            for (int j = 0; j < 4; j++)
                C[(long)(row + j) * ldc + col] = acc[tm][tn][j];
        }
    }
}

// f32 -> bf16 for 6 tensors in one launch; blockIdx.y selects tensor
__global__ __launch_bounds__(256)
void cvt6(const float* __restrict__ s0, const float* __restrict__ s1,
          const float* __restrict__ s2, const float* __restrict__ s3,
          const float* __restrict__ s4, const float* __restrict__ s5,
          __bf16* __restrict__ dX, __bf16* __restrict__ dW)
{
    const int y = blockIdx.y;
    const float* src = y == 0 ? s0 : y == 1 ? s1 : y == 2 ? s2
                     : y == 3 ? s3 : y == 4 ? s4 : s5;
    const long n = (y < 3) ? 8388608L : 1048576L;
    __bf16* dst = (y < 3) ? dX + (long)y * 8388608L : dW + (long)(y - 3) * 1048576L;

    long i = ((long)blockIdx.x * 256 + threadIdx.x) * 8;
    const long stride = (long)gridDim.x * 2048;
    for (; i < n; i += stride) {
        float4 a = *(const float4*)(src + i);
        float4 b = *(const float4*)(src + i + 4);
        bf16x8 v;
        v[0] = (__bf16)a.x; v[1] = (__bf16)a.y; v[2] = (__bf16)a.z; v[3] = (__bf16)a.w;
        v[4] = (__bf16)b.x; v[5] = (__bf16)b.y; v[6] = (__bf16)b.z; v[7] = (__bf16)b.w;
        *(bf16x8*)(dst + i) = v;
    }
}

// Wave-per-row causal softmax: one 64-lane wave owns row q. float4 loads,
// shuffle-only reductions, bf16x4 stores in-place over S (row stride 4096).
// Compile-time-unrolled chunk loops with i<ni guards keep v[] in registers.
__global__ __launch_bounds__(256)
void softmax_causal(float* __restrict__ S)
{
    const int q = (blockIdx.x << 2) + (threadIdx.x >> 6);
    const int lane = threadIdx.x & 63;
    const long rowoff = (long)blockIdx.y * 2048 + q;
    const float* Srow = S + rowoff * 2048;
    __bf16* Prow = (__bf16*)S + rowoff * 4096;   // aliases the same row
    const int ni = ((q | 127) + 256) >> 8;       // live 256-elem chunks

    float4 v[8];
    float mx = -1e30f;
#pragma unroll
    for (int i = 0; i < 8; i++) {
        if (i < ni) {
            const int e0 = ((i << 6) + lane) << 2;
            float4 t = *(const float4*)(Srow + e0);
            t.x = (e0     <= q) ? t.x : -1e30f;
            t.y = (e0 + 1 <= q) ? t.y : -1e30f;
            t.z = (e0 + 2 <= q) ? t.z : -1e30f;
            t.w = (e0 + 3 <= q) ? t.w : -1e30f;
            v[i] = t;
            mx = fmaxf(mx, fmaxf(fmaxf(t.x, t.y), fmaxf(t.z, t.w)));
        }
    }
    for (int off = 32; off; off >>= 1) mx = fmaxf(mx, __shfl_xor(mx, off));

    float s = 0.f;
#pragma unroll
    for (int i = 0; i < 8; i++) {
        if (i < ni) {
            float4 t = v[i];
            t.x = __expf(t.x - mx); t.y = __expf(t.y - mx);
            t.z = __expf(t.z - mx); t.w = __expf(t.w - mx);
            v[i] = t;
            s += (t.x + t.y) + (t.z + t.w);
        }
    }
    for (int off = 32; off; off >>= 1) s += __shfl_xor(s, off);
    const float inv = 1.f / s;

    // wave-lockstep: all Srow loads above precede these aliasing stores
#pragma unroll
    for (int i = 0; i < 8; i++) {
        if (i < ni) {
            const int e0 = ((i << 6) + lane) << 2;
            bf16x4 o;
            o[0] = (__bf16)(v[i].x * inv); o[1] = (__bf16)(v[i].y * inv);
            o[2] = (__bf16)(v[i].z * inv); o[3] = (__bf16)(v[i].w * inv);
            *(bf16x4*)(Prow + e0) = o;
        }
    }
}

extern "C" void kernel_launch(void* const* d_in, const int* in_sizes, int n_in,
                              void* d_out, int out_size, void* d_ws, size_t ws_size,
                              hipStream_t stream) {
    const float* query = (const float*)d_in[0];
    const float* key   = (const float*)d_in[1];
    const float* value = (const float*)d_in[2];
    // d_in[3] = mask : deterministic causal triu -> applied by index, ignored here
    const float* Wq = (const float*)d_in[4];
    const float* bq = (const float*)d_in[5];
    const float* Wk = (const float*)d_in[6];
    const float* bk = (const float*)d_in[7];
    const float* Wv = (const float*)d_in[8];
    const float* bv = (const float*)d_in[9];
    float* out = (float*)d_out;

    char* ws = (char*)d_ws;
    const long MB = 1L << 20;
    __bf16* QKV = (__bf16*)(ws);             // [3][8192][1024] (z=2 slab unused)
    __bf16* Vt  = (__bf16*)(ws + 48 * MB);   // [4][1024][2048]
    float*  S   = (float*) (ws + 64 * MB);   // [4][2048][2048]
    __bf16* Xb  = (__bf16*)(ws + 64 * MB);   // overlap, dead before S written
    __bf16* Wb  = (__bf16*)(ws + 112 * MB);

    const dim3 blk(256);

    // 0) f32 -> bf16 conversions (single launch)
    cvt6<<<dim3(1024, 6), blk, 0, stream>>>(query, key, value, Wq, Wk, Wv, Xb, Wb);

    // 1) merged projections (all-bf16; coalesced epilogues; z==2 -> Vt transposed)
    gemm_projb<<<dim3(8, 64, 3), blk, 0, stream>>>(
        Xb, Wb, bq, bk, bv, 1.f / 32.f, QKV, Vt);

    // 2) scores S[n][q][k] = Qs[q].Kp[k]  — tri-compact equal-work grid
    gemm_bt<1><<<dim3(136, 1, 4), blk, 0, stream>>>(QKV, QKV + 8388608L, S,
        1024, 1024, 1024, 2048, 2048L * 1024, 2048L * 1024, 2048L * 2048);

    // 3) causal softmax (wave-per-row, register-resident, in-place S -> P bf16)
    softmax_causal<<<dim3(512, 4), blk, 0, stream>>>(S);

    // 4) y = P . V via Vt, causal K truncation, pair-balanced row order
    gemm_bt<2><<<dim3(8, 16, 4), blk, 0, stream>>>((__bf16*)S, Vt, out,
        2048, 4096, 2048, 1024, 2048L * 4096, 1024L * 2048, 2048L * 1024);
}

// Round 16
// 174.714 us; speedup vs baseline: 1.1672x; 1.0052x over previous
//
#include <hip/hip_runtime.h>
#include <hip/hip_bf16.h>

// Self-attention: y = softmax_causal((Xq Wq^T + bq)(Xk Wk^T + bk)^T / 32) (Xv Wv^T + bv)
// N=4, K=2048, M=DQ=DV=1024.
//
// BEST-OF COMPOSITE (r16): each sub-kernel at its best measured config.
//   0) cvt6          : {query,key,value,Wq,Wk,Wv} -> bf16, one launch (~25us, BW floor)
//   1) gemm_projb    : merged projections, all-bf16 128^2 2-phase (62us, 830 TF).
//                      z<2: DIRECT epilogue stores (r12/r14-verified; r15's bounce
//                      cost +1.5us, +131K conflicts — reverted).
//                      z==2: V transposed to Vt via LDS bounce (kills transpose pass).
//   2) gemm_bt<1>    : S = Qs . Kp^T (f32), tri-compact equal-work causal grid
//   3) softmax_causal: wave-per-row, register-resident (rule-#20-safe unroll+guard)
//   4) gemm_bt<2>    : y = P . Vt, causal K truncation, pair-balanced row order
//
// Workspace (128 MiB): QKV bf16 [3][8192][1024] @0 (z=2 slab unused); Vt @48M;
//   S f32 [4][2048][2048] @64M (aliased per-row by P bf16, row stride 4096);
//   overlap (dead before S): Xb bf16 [3][8192][1024] @64M; Wb @112M

typedef __bf16 bf16x8 __attribute__((ext_vector_type(8)));
typedef __bf16 bf16x4 __attribute__((ext_vector_type(4)));
typedef float  f32x4  __attribute__((ext_vector_type(4)));

#define BM 128
#define BN 128
#define BKK 64

// byte offset into a [rows][64] bf16 LDS tile, 16B slots XOR-swizzled by row
__device__ __forceinline__ int swz(int row, int slot) {
    return row * 128 + (((slot) ^ (row & 7)) << 4);
}

__device__ __forceinline__ void gload16(const __bf16* g, __bf16* l) {
    __builtin_amdgcn_global_load_lds((const __attribute__((address_space(1))) void*)g,
                                     (__attribute__((address_space(3))) void*)l, 16, 0, 0);
}

// T1: bijective XCD-chunked remap (m204)
__device__ __forceinline__ void xcd_remap(int& bx, int& by, int& bz) {
    const int nx = gridDim.x, ny = gridDim.y;
    const int nwg = nx * ny * gridDim.z;
    const int flat = blockIdx.x + nx * (blockIdx.y + ny * blockIdx.z);
    const int q = nwg >> 3, r = nwg & 7;
    const int xcd = flat & 7, idx = flat >> 3;
    const int l = (xcd < r ? xcd * (q + 1) : r * (q + 1) + (xcd - r) * q) + idx;
    bx = l % nx; by = (l / nx) % ny; bz = l / (nx * ny);
}

// ============== merged projection GEMM (all-bf16, r12-verified epilogues) ==============
__global__ __launch_bounds__(256)
void gemm_projb(const __bf16* __restrict__ Xb, const __bf16* __restrict__ Wb,
                const float* __restrict__ b0, const float* __restrict__ b1,
                const float* __restrict__ b2, float scaleQ,
                __bf16* __restrict__ QKV, __bf16* __restrict__ Vt)
{
    __shared__ char smem[65536];
    __bf16* smA = (__bf16*)smem;            // [2][128*64]
    __bf16* smB = (__bf16*)(smem + 32768);  // [2][128*64]

    int bx, by, bz;
    xcd_remap(bx, by, bz);                  // grid (8, 64, 3)
    const int m0 = by * BM, n0 = bx * BN;
    const int z = bz;
    const __bf16* Az = Xb + (long)z * 8388608L;
    const __bf16* Bz = Wb + (long)z * 1048576L;

    const int tid = threadIdx.x;
    const int wid = tid >> 6, lane = tid & 63;
    const int wm = (wid >> 1) * 64, wn = (wid & 1) * 64;  // 2x2 waves, 64x64 each
    const int g = lane >> 4, li = lane & 15;
    const int rl = lane >> 3;               // row within 8-row segment
    const int sg = (lane & 7) ^ rl;         // pre-swizzled 16B slot in global

    f32x4 acc[4][4];
#pragma unroll
    for (int i = 0; i < 4; i++)
#pragma unroll
        for (int j = 0; j < 4; j++)
            acc[i][j] = (f32x4){0.f, 0.f, 0.f, 0.f};

    auto STAGE = [&](int buf, int k0) {     // async global->LDS, both operands
#pragma unroll
        for (int i = 0; i < 4; i++) {
            const int seg = i * 4 + wid;
            const int r = seg * 8 + rl;
            gload16(Az + (long)(m0 + r) * 1024 + k0 + sg * 8, smA + buf * 8192 + seg * 512);
            gload16(Bz + (long)(n0 + r) * 1024 + k0 + sg * 8, smB + buf * 8192 + seg * 512);
        }
    };

    auto COMPUTE = [&](int buf) {
        const char* bA = (const char*)(smA + buf * 8192);
        const char* bB = (const char*)(smB + buf * 8192);
#pragma unroll
        for (int kk = 0; kk < 2; kk++) {
            const int slot = kk * 4 + g;
            bf16x8 af[4], bfv[4];
#pragma unroll
            for (int t = 0; t < 4; t++)
                af[t] = *(const bf16x8*)(bA + swz(wm + t * 16 + li, slot));
#pragma unroll
            for (int t = 0; t < 4; t++)
                bfv[t] = *(const bf16x8*)(bB + swz(wn + t * 16 + li, slot));
#pragma unroll
            for (int tm = 0; tm < 4; tm++)
#pragma unroll
                for (int tn = 0; tn < 4; tn++)
                    acc[tm][tn] = __builtin_amdgcn_mfma_f32_16x16x32_bf16(
                        af[tm], bfv[tn], acc[tm][tn], 0, 0, 0);
        }
    };

    const int nt = 16;                      // K = 1024 / 64
    STAGE(0, 0);
    __syncthreads();
    int cur = 0;
    for (int t = 0; t < nt - 1; ++t) {
        STAGE(cur ^ 1, (t + 1) * BKK);      // prefetch flies under compute
        COMPUTE(cur);
        __syncthreads();
        cur ^= 1;
    }
    COMPUTE(cur);

    // ---- epilogue: C/D layout col = lane&15, row = 4*(lane>>4)+reg ----
    if (z < 2) {
        // direct stores (r12/r14-verified 62.0us config)
        const float scale = (z == 0) ? scaleQ : 1.f;
        const float* bias = (z == 0) ? b0 : b1;
        __bf16* C = QKV + (long)z * 8388608L;
#pragma unroll
        for (int tm = 0; tm < 4; tm++)
#pragma unroll
            for (int tn = 0; tn < 4; tn++) {
                const int row = m0 + wm + tm * 16 + g * 4;
                const int col = n0 + wn + tn * 16 + li;
                const float b = bias[col];
#pragma unroll
                for (int j = 0; j < 4; j++)
                    C[(long)(row + j) * 1024 + col] = (__bf16)((acc[tm][tn][j] + b) * scale);
            }
    } else {
        // V: bias-add, write TRANSPOSED to Vt via LDS bounce (2-way pattern, free)
        __syncthreads();                    // done reading smA/smB; reuse as T[128][136]
        __bf16* T = (__bf16*)smem;
#pragma unroll
        for (int tm = 0; tm < 4; tm++)
#pragma unroll
            for (int tn = 0; tn < 4; tn++) {
                const int rowl = wm + tm * 16 + g * 4;      // k-local
                const int coll = wn + tn * 16 + li;         // d-local
                const float b = b2[n0 + coll];
#pragma unroll
                for (int j = 0; j < 4; j++)
                    T[coll * 136 + rowl + j] = (__bf16)(acc[tm][tn][j] + b);
            }
        __syncthreads();
        const long nb = m0 >> 11;           // batch index
        const int kbase = m0 & 2047;
        __bf16* Vtb = Vt + nb * 2097152L;   // [1024][2048] per batch
#pragma unroll
        for (int it = 0; it < 8; it++) {
            const int lin = tid + 256 * it;  // 0..2047
            const int c = lin >> 4;          // d-local 0..127
            const int r0 = (lin & 15) * 8;   // k-local 0..120
            bf16x8 v = *(const bf16x8*)(T + c * 136 + r0);
            *(bf16x8*)(Vtb + (long)(n0 + c) * 2048 + kbase + r0) = v;
        }
    }
}

// ================= 128x128 2-phase GEMM for scores / PV =================
// MODE 1: C f32; TRI-COMPACT causal grid (grid.x = 136 triangle-encoded blocks).
// MODE 2: C f32; K truncated at m0+BM; by-permutation balances per-CU pair work.
template<int MODE>
__global__ __launch_bounds__(256)
void gemm_bt(const __bf16* __restrict__ Ap, const __bf16* __restrict__ Bp,
             void* __restrict__ Cp, int Kd, int lda, int ldb, int ldc,
             long strideA, long strideB, long strideC)
{
    __shared__ __bf16 smA[2][BM * BKK];
    __shared__ __bf16 smB[2][BN * BKK];

    int bx, by, bz;
    xcd_remap(bx, by, bz);

    if (MODE == 1) {
        // triangle decode: t -> (row by, col bx), bx <= by
        const int t = bx;
        int r = (int)((sqrtf(8.f * t + 1.f) - 1.f) * 0.5f);
        while ((r + 1) * (r + 2) / 2 <= t) r++;
        while (r * (r + 1) / 2 > t) r--;
        by = r;
        bx = t - r * (r + 1) / 2;
    }
    if (MODE == 2) {
        // balance CU pairs (logical by, by+4): f(b)+f(b+4) == 15 for all b
        const int t = by >> 2;
        by = (t == 0) ? by : (t == 1) ? 19 - by : (t == 2) ? by - 4 : 23 - by;
    }

    const int tid = threadIdx.x;
    const int m0 = by * BM;
    const int n0 = bx * BN;

    const long z = bz;
    int kEnd = Kd;
    if (MODE == 2) { int lim = m0 + BM; kEnd = lim < Kd ? lim : Kd; }

    const int wid = tid >> 6, lane = tid & 63;
    const int wm = (wid >> 1) * 64, wn = (wid & 1) * 64;
    const int g = lane >> 4, li = lane & 15;
    const int rl = lane >> 3;
    const int sg = (lane & 7) ^ rl;
    const __bf16* Az = Ap + z * strideA;
    const __bf16* Bz = Bp + z * strideB;

    f32x4 acc[4][4];
    for (int i = 0; i < 4; i++)
        for (int j = 0; j < 4; j++)
            acc[i][j] = (f32x4){0.f, 0.f, 0.f, 0.f};

    auto STAGE = [&](int buf, int k0) {
        for (int i = 0; i < 4; i++) {
            const int seg = i * 4 + wid;
            const int r = seg * 8 + rl;
            gload16(Az + (long)(m0 + r) * lda + k0 + sg * 8, &smA[buf][seg * 512]);
            gload16(Bz + (long)(n0 + r) * ldb + k0 + sg * 8, &smB[buf][seg * 512]);
        }
    };

    auto COMPUTE = [&](int buf) {
        for (int kk = 0; kk < 2; kk++) {
            const int slot = kk * 4 + g;
            bf16x8 af[4], bfv[4];
            for (int t = 0; t < 4; t++)
                af[t] = *(const bf16x8*)((const char*)&smA[buf][0] + swz(wm + t * 16 + li, slot));
            for (int t = 0; t < 4; t++)
                bfv[t] = *(const bf16x8*)((const char*)&smB[buf][0] + swz(wn + t * 16 + li, slot));
            for (int tm = 0; tm < 4; tm++)
                for (int tn = 0; tn < 4; tn++)
                    acc[tm][tn] = __builtin_amdgcn_mfma_f32_16x16x32_bf16(
                        af[tm], bfv[tn], acc[tm][tn], 0, 0, 0);
        }
    };

    const int nt = kEnd / BKK;
    STAGE(0, 0);
    __syncthreads();
    int cur = 0;
    for (int t = 0; t < nt - 1; ++t) {
        STAGE(cur ^ 1, (t + 1) * BKK);
        COMPUTE(cur);
        __syncthreads();
        cur ^= 1;
    }
    COMPUTE(cur);

    for (int tm = 0; tm < 4; tm++) {
        for (int tn = 0; tn < 4; tn++) {
            const int row = m0 + wm + tm * 16 + g * 4;
            const int col = n0 + wn + tn * 16 + li;
            float* C = (float*)Cp + z * strideC;
            for (int j = 0; j < 4; j++)
                C[(long)(row + j) * ldc + col] = acc[tm][tn][j];
        }
    }
}

// f32 -> bf16 for 6 tensors in one launch; blockIdx.y selects tensor
__global__ __launch_bounds__(256)
void cvt6(const float* __restrict__ s0, const float* __restrict__ s1,
          const float* __restrict__ s2, const float* __restrict__ s3,
          const float* __restrict__ s4, const float* __restrict__ s5,
          __bf16* __restrict__ dX, __bf16* __restrict__ dW)
{
    const int y = blockIdx.y;
    const float* src = y == 0 ? s0 : y == 1 ? s1 : y == 2 ? s2
                     : y == 3 ? s3 : y == 4 ? s4 : s5;
    const long n = (y < 3) ? 8388608L : 1048576L;
    __bf16* dst = (y < 3) ? dX + (long)y * 8388608L : dW + (long)(y - 3) * 1048576L;

    long i = ((long)blockIdx.x * 256 + threadIdx.x) * 8;
    const long stride = (long)gridDim.x * 2048;
    for (; i < n; i += stride) {
        float4 a = *(const float4*)(src + i);
        float4 b = *(const float4*)(src + i + 4);
        bf16x8 v;
        v[0] = (__bf16)a.x; v[1] = (__bf16)a.y; v[2] = (__bf16)a.z; v[3] = (__bf16)a.w;
        v[4] = (__bf16)b.x; v[5] = (__bf16)b.y; v[6] = (__bf16)b.z; v[7] = (__bf16)b.w;
        *(bf16x8*)(dst + i) = v;
    }
}

// Wave-per-row causal softmax: one 64-lane wave owns row q. float4 loads,
// shuffle-only reductions, bf16x4 stores in-place over S (row stride 4096).
// Compile-time-unrolled chunk loops with i<ni guards keep v[] in registers.
__global__ __launch_bounds__(256)
void softmax_causal(float* __restrict__ S)
{
    const int q = (blockIdx.x << 2) + (threadIdx.x >> 6);
    const int lane = threadIdx.x & 63;
    const long rowoff = (long)blockIdx.y * 2048 + q;
    const float* Srow = S + rowoff * 2048;
    __bf16* Prow = (__bf16*)S + rowoff * 4096;   // aliases the same row
    const int ni = ((q | 127) + 256) >> 8;       // live 256-elem chunks

    float4 v[8];
    float mx = -1e30f;
#pragma unroll
    for (int i = 0; i < 8; i++) {
        if (i < ni) {
            const int e0 = ((i << 6) + lane) << 2;
            float4 t = *(const float4*)(Srow + e0);
            t.x = (e0     <= q) ? t.x : -1e30f;
            t.y = (e0 + 1 <= q) ? t.y : -1e30f;
            t.z = (e0 + 2 <= q) ? t.z : -1e30f;
            t.w = (e0 + 3 <= q) ? t.w : -1e30f;
            v[i] = t;
            mx = fmaxf(mx, fmaxf(fmaxf(t.x, t.y), fmaxf(t.z, t.w)));
        }
    }
    for (int off = 32; off; off >>= 1) mx = fmaxf(mx, __shfl_xor(mx, off));

    float s = 0.f;
#pragma unroll
    for (int i = 0; i < 8; i++) {
        if (i < ni) {
            float4 t = v[i];
            t.x = __expf(t.x - mx); t.y = __expf(t.y - mx);
            t.z = __expf(t.z - mx); t.w = __expf(t.w - mx);
            v[i] = t;
            s += (t.x + t.y) + (t.z + t.w);
        }
    }
    for (int off = 32; off; off >>= 1) s += __shfl_xor(s, off);
    const float inv = 1.f / s;

    // wave-lockstep: all Srow loads above precede these aliasing stores
#pragma unroll
    for (int i = 0; i < 8; i++) {
        if (i < ni) {
            const int e0 = ((i << 6) + lane) << 2;
            bf16x4 o;
            o[0] = (__bf16)(v[i].x * inv); o[1] = (__bf16)(v[i].y * inv);
            o[2] = (__bf16)(v[i].z * inv); o[3] = (__bf16)(v[i].w * inv);
            *(bf16x4*)(Prow + e0) = o;
        }
    }
}

extern "C" void kernel_launch(void* const* d_in, const int* in_sizes, int n_in,
                              void* d_out, int out_size, void* d_ws, size_t ws_size,
                              hipStream_t stream) {
    const float* query = (const float*)d_in[0];
    const float* key   = (const float*)d_in[1];
    const float* value = (const float*)d_in[2];
    // d_in[3] = mask : deterministic causal triu -> applied by index, ignored here
    const float* Wq = (const float*)d_in[4];
    const float* bq = (const float*)d_in[5];
    const float* Wk = (const float*)d_in[6];
    const float* bk = (const float*)d_in[7];
    const float* Wv = (const float*)d_in[8];
    const float* bv = (const float*)d_in[9];
    float* out = (float*)d_out;

    char* ws = (char*)d_ws;
    const long MB = 1L << 20;
    __bf16* QKV = (__bf16*)(ws);             // [3][8192][1024] (z=2 slab unused)
    __bf16* Vt  = (__bf16*)(ws + 48 * MB);   // [4][1024][2048]
    float*  S   = (float*) (ws + 64 * MB);   // [4][2048][2048]
    __bf16* Xb  = (__bf16*)(ws + 64 * MB);   // overlap, dead before S written
    __bf16* Wb  = (__bf16*)(ws + 112 * MB);

    const dim3 blk(256);

    // 0) f32 -> bf16 conversions (single launch)
    cvt6<<<dim3(1024, 6), blk, 0, stream>>>(query, key, value, Wq, Wk, Wv, Xb, Wb);

    // 1) merged projections (all-bf16; direct z<2 epilogue; z==2 -> Vt transposed)
    gemm_projb<<<dim3(8, 64, 3), blk, 0, stream>>>(
        Xb, Wb, bq, bk, bv, 1.f / 32.f, QKV, Vt);

    // 2) scores S[n][q][k] = Qs[q].Kp[k]  — tri-compact equal-work grid
    gemm_bt<1><<<dim3(136, 1, 4), blk, 0, stream>>>(QKV, QKV + 8388608L, S,
        1024, 1024, 1024, 2048, 2048L * 1024, 2048L * 1024, 2048L * 2048);

    // 3) causal softmax (wave-per-row, register-resident, in-place S -> P bf16)
    softmax_causal<<<dim3(512, 4), blk, 0, stream>>>(S);

    // 4) y = P . V via Vt, causal K truncation, pair-balanced row order
    gemm_bt<2><<<dim3(8, 16, 4), blk, 0, stream>>>((__bf16*)S, Vt, out,
        2048, 4096, 2048, 1024, 2048L * 4096, 1024L * 2048, 2048L * 1024);
}